// Round 1
// 172.916 us; speedup vs baseline: 1.0113x; 1.0113x over previous
//
#include <hip/hip_runtime.h>

#define B_ 2
#define S_ 2048
#define D_ 1024
#define H_ 16
#define DK_ 64
#define M_ (B_ * S_)   // 4096
#define N_ (3 * D_)    // 3072

typedef __bf16 bf16x8 __attribute__((ext_vector_type(8)));
typedef short s8vec __attribute__((ext_vector_type(8)));
typedef float f4vec __attribute__((ext_vector_type(4)));

static __device__ __forceinline__ ushort f2b(float f) {
  union { float f; unsigned u; } v; v.f = f;
  unsigned u = v.u;
  u += 0x7FFFu + ((u >> 16) & 1u);   // RNE to bf16
  return (ushort)(u >> 16);
}

static __device__ __forceinline__ unsigned pk2(float a, float b) {
#if __has_builtin(__builtin_amdgcn_cvt_pk_bf16_f32)
  typedef __bf16 b2 __attribute__((ext_vector_type(2)));
  b2 r = __builtin_amdgcn_cvt_pk_bf16_f32(a, b);
  return __builtin_bit_cast(unsigned, r);
#else
  return (unsigned)f2b(a) | ((unsigned)f2b(b) << 16);
#endif
}

static __device__ __forceinline__ float exp2f_fast(float x) {
#if __has_builtin(__builtin_amdgcn_exp2f)
  return __builtin_amdgcn_exp2f(x);
#else
  return __expf(x * 0.6931471805599453f);   // 2^x = e^(x ln2)
#endif
}

static __device__ __forceinline__ f4vec mfma16(s8vec a, s8vec b, f4vec c) {
  return __builtin_amdgcn_mfma_f32_16x16x32_bf16(
      __builtin_bit_cast(bf16x8, a), __builtin_bit_cast(bf16x8, b), c, 0, 0, 0);
}

static __device__ __forceinline__ void gl_lds16(const ushort* g, ushort* l) {
  __builtin_amdgcn_global_load_lds(
      (const __attribute__((address_space(1))) unsigned*)g,
      (__attribute__((address_space(3))) unsigned*)l, 16, 0, 0);
}

// raw workgroup barrier: drains LDS (lgkmcnt) only — in-flight GLOBAL loads to
// VGPRs stay outstanding across the barrier (the whole point of reg-prefetch).
// 0xC07F = vmcnt(63) expcnt(7) lgkmcnt(0). asm clobbers stop compiler reordering.
static __device__ __forceinline__ void wg_barrier_lds() {
  asm volatile("" ::: "memory");
  __builtin_amdgcn_s_waitcnt(0xC07F);
  __builtin_amdgcn_s_barrier();
  asm volatile("" ::: "memory");
}

// ---- convert x (fp32) -> bf16, 4 elems/thread ----
__global__ void cvt_x(const float* __restrict__ x, ushort* __restrict__ xb) {
  int i = blockIdx.x * 256 + threadIdx.x;
  float4 v = ((const float4*)x)[i];
  ushort4 o;
  o.x = f2b(v.x); o.y = f2b(v.y); o.z = f2b(v.z); o.w = f2b(v.w);
  ((ushort4*)xb)[i] = o;
}

// ---- cvt_w via LDS transpose: W[h][d][k] fp32 -> wbt[(w*1024+h*64+k)*1024+d] bf16 ----
// Wq (w==0) is pre-scaled by log2(e) so attn can use exp2 directly:
// exp(q·k) == exp2((log2e·q)·k).
__global__ __launch_bounds__(256) void cvt_w(const float* __restrict__ Wq,
                                             const float* __restrict__ Wk,
                                             const float* __restrict__ Wv,
                                             ushort* __restrict__ wbt) {
  __shared__ ushort T[64 * 72];
  const int w = blockIdx.z, h = blockIdx.y, d0 = blockIdx.x * 64;
  const float* W = (w == 0) ? Wq : (w == 1) ? Wk : Wv;
  const float sc = (w == 0) ? 1.4426950408889634f : 1.0f;
  const float* src = W + (size_t)h * 65536 + (size_t)d0 * 64;   // [64 d][64 k]
  const int t = threadIdx.x;
#pragma unroll
  for (int j = 0; j < 4; ++j) {
    int idx = j * 256 + t;
    int dr = idx >> 4, kc = (idx & 15) * 4;
    float4 v = *(const float4*)(src + dr * 64 + kc);
    T[(kc + 0) * 72 + dr] = f2b(v.x * sc);
    T[(kc + 1) * 72 + dr] = f2b(v.y * sc);
    T[(kc + 2) * 72 + dr] = f2b(v.z * sc);
    T[(kc + 3) * 72 + dr] = f2b(v.w * sc);
  }
  __syncthreads();
  const int kk = t >> 2, dcg = (t & 3) * 16;
  ushort* dst = wbt + ((size_t)w * 1024 + h * 64 + kk) * 1024 + d0 + dcg;
  *(s8vec*)dst       = *(const s8vec*)&T[kk * 72 + dcg];
  *(s8vec*)(dst + 8) = *(const s8vec*)&T[kk * 72 + dcg + 8];
}

// ---- fused QKV projection: C[4096][3072] = X[4096][1024] @ Wbt^T (m97 structure) ----
__global__ __launch_bounds__(256) void proj_gemm(const ushort* __restrict__ xb,
                                                 const ushort* __restrict__ wbt,
                                                 ushort* __restrict__ qkv) {
  __shared__ __attribute__((aligned(16))) ushort As[128 * 64];
  __shared__ __attribute__((aligned(16))) ushort Bs[128 * 64];
  const int tid = threadIdx.x, wid = tid >> 6, lane = tid & 63;
  const int quad = lane >> 4, l15 = lane & 15;
  const int wm = wid & 1, wn = wid >> 1;
  const int m0 = blockIdx.x * 128, n0 = blockIdx.y * 128;

  f4vec acc[4][4];
#pragma unroll
  for (int mb = 0; mb < 4; mb++)
#pragma unroll
    for (int nb = 0; nb < 4; nb++)
#pragma unroll
      for (int i = 0; i < 4; i++) acc[mb][nb][i] = 0.f;

  const int sr = tid >> 3, sg = tid & 7;
  const int lg = sg ^ (sr & 7);
  const ushort* Ab = xb + (size_t)m0 * D_;
  const ushort* Bb = wbt + (size_t)n0 * D_;

  for (int k0 = 0; k0 < D_; k0 += 64) {
    __syncthreads();
#pragma unroll
    for (int j = 0; j < 4; ++j) {
      int r = j * 32 + sr;
      gl_lds16(Ab + (size_t)r * D_ + k0 + lg * 8, &As[j * 2048 + wid * 512]);
      gl_lds16(Bb + (size_t)r * D_ + k0 + lg * 8, &Bs[j * 2048 + wid * 512]);
    }
    __syncthreads();

#pragma unroll
    for (int kb = 0; kb < 2; ++kb) {
      s8vec af[4], bf[4];
#pragma unroll
      for (int mb = 0; mb < 4; ++mb) {
        int m = wm * 64 + mb * 16 + l15;
        int gpos = (kb * 4 + quad) ^ (m & 7);
        af[mb] = *(const s8vec*)&As[m * 64 + gpos * 8];
      }
#pragma unroll
      for (int nb = 0; nb < 4; ++nb) {
        int n = wn * 64 + nb * 16 + l15;
        int gpos = (kb * 4 + quad) ^ (n & 7);
        bf[nb] = *(const s8vec*)&Bs[n * 64 + gpos * 8];
      }
#pragma unroll
      for (int mb = 0; mb < 4; ++mb)
#pragma unroll
        for (int nb = 0; nb < 4; ++nb)
          acc[mb][nb] = mfma16(af[mb], bf[nb], acc[mb][nb]);
    }
  }

  const size_t per = (size_t)B_ * H_ * S_ * DK_;
  const int w = n0 >> 10;
  if (w == 2) {
    ushort* vt = qkv + 2 * per;
#pragma unroll
    for (int mb = 0; mb < 4; ++mb)
#pragma unroll
      for (int nb = 0; nb < 4; ++nb)
#pragma unroll
        for (int i = 0; i < 4; ++i) {
          int m = m0 + wm * 64 + mb * 16 + quad * 4 + i;
          int b = m >> 11, s = m & 2047;
          int n1 = (n0 & 1023) + wn * 64 + nb * 16 + l15;
          vt[((size_t)b * 1024 + n1) * S_ + s] = f2b(acc[mb][nb][i]);
        }
  } else {
#pragma unroll
    for (int mb = 0; mb < 4; ++mb)
#pragma unroll
      for (int nb = 0; nb < 4; ++nb)
#pragma unroll
        for (int i = 0; i < 4; ++i) {
          int m = m0 + wm * 64 + mb * 16 + quad * 4 + i;
          int b = m >> 11, s = m & 2047;
          int n1 = (n0 & 1023) + wn * 64 + nb * 16 + l15;
          qkv[(size_t)w * per + (((size_t)b * H_ + (n1 >> 6)) * S_ + s) * 64 + (n1 & 63)] =
              f2b(acc[mb][nb][i]);
        }
  }
}

// ---- flash attention v4: 256 thr (4 waves x 32 Q-rows = Q-tile 128), K-tile 128.
// Swapped QK^T (mfma(K,Q)) gives S^T: each lane owns ONE q-column (q = l15) with
// 4 consecutive keys per 16-key block -> P is packed in registers (cvt_pk) and
// transposed into the PV B-fragment with v_permlane32/16_swap. No Ps LDS buffer:
// LDS = 32 KB (Ks+Vt only), LDS traffic per wave-tile 40 KB for 64 MFMAs
// (was 45 KB for 32). Register-prefetch double buffering + lgkm-only barriers
// kept from v3. Scores arrive pre-scaled by log2e (cvt_w) -> exp2 directly.
__global__ __launch_bounds__(256) void attn(const ushort* __restrict__ qg,
                                            const ushort* __restrict__ kg,
                                            const ushort* __restrict__ vtg,
                                            float* __restrict__ out) {
  __shared__ __attribute__((aligned(16))) ushort Ks[128 * 64];     // [key][d] swizzled
  __shared__ __attribute__((aligned(16))) ushort Vt[2][64 * 64];   // [half][dv][key] swizzled
  const int qt = blockIdx.x, bh = blockIdx.y;
  const int b = bh >> 4, h = bh & 15;
  const int tid = threadIdx.x, wid = tid >> 6, lane = tid & 63;
  const int quad = lane >> 4, l15 = lane & 15, l7 = l15 & 7;

  // Q B-fragments: 32 q-rows per wave (2 blocks of 16), loaded once.
  const ushort* qbase = qg + ((size_t)bh * S_ + qt * 128 + wid * 32) * DK_;
  s8vec bq[2][2];
#pragma unroll
  for (int qb = 0; qb < 2; ++qb)
#pragma unroll
    for (int kc = 0; kc < 2; ++kc)
      bq[qb][kc] = *(const s8vec*)(qbase + (size_t)(qb * 16 + l15) * DK_ + kc * 32 + quad * 8);

  f4vec o[4][2];            // O^T frags: [dv-block][q-block]
  float lsum[2] = {0.f, 0.f};
#pragma unroll
  for (int nb = 0; nb < 4; ++nb)
#pragma unroll
    for (int qb = 0; qb < 2; ++qb)
#pragma unroll
      for (int i = 0; i < 4; ++i) o[nb][qb][i] = 0.f;

  // staging: 256 threads stage 128x64 K + 64x128 V per tile.
  // thread t -> K rows {r5, r5+32, r5+64, r5+96}, V dv-rows {r5, r5+32} x halves;
  // LDS[row][gs] holds global group gs^(row&7)  (row&7 invariant under +32).
  const int r5 = tid >> 3, gs = tid & 7;
  const int gk = gs ^ (r5 & 7);
  const ushort* kb_ = kg + (size_t)bh * S_ * DK_;
  const ushort* vb_ = vtg + (size_t)bh * 64 * S_;

  s8vec kr[4], vr[4];
#pragma unroll
  for (int j = 0; j < 4; ++j)
    kr[j] = *(const s8vec*)(kb_ + (size_t)(j * 32 + r5) * DK_ + gk * 8);
#pragma unroll
  for (int jd = 0; jd < 2; ++jd)
#pragma unroll
    for (int hf = 0; hf < 2; ++hf)
      vr[jd * 2 + hf] = *(const s8vec*)(vb_ + (size_t)(jd * 32 + r5) * S_ + hf * 64 + gk * 8);

  for (int kt = 0; kt < S_ / 128; ++kt) {
    wg_barrier_lds();                       // readers of previous tile done
#pragma unroll
    for (int j = 0; j < 4; ++j)             // vmcnt auto-waits these regs
      *(s8vec*)&Ks[(j * 32 + r5) * 64 + gs * 8] = kr[j];
#pragma unroll
    for (int jd = 0; jd < 2; ++jd)
#pragma unroll
      for (int hf = 0; hf < 2; ++hf)
        *(s8vec*)&Vt[hf][(jd * 32 + r5) * 64 + gs * 8] = vr[jd * 2 + hf];
    if (kt + 1 < S_ / 128) {                // prefetch next tile; stays in flight
      const ushort* kn = kb_ + (size_t)(kt + 1) * 128 * DK_;
#pragma unroll
      for (int j = 0; j < 4; ++j)
        kr[j] = *(const s8vec*)(kn + (size_t)(j * 32 + r5) * DK_ + gk * 8);
      const ushort* vn = vb_ + (kt + 1) * 128;
#pragma unroll
      for (int jd = 0; jd < 2; ++jd)
#pragma unroll
        for (int hf = 0; hf < 2; ++hf)
          vr[jd * 2 + hf] = *(const s8vec*)(vn + (size_t)(jd * 32 + r5) * S_ + hf * 64 + gk * 8);
    }
    wg_barrier_lds();                       // staging writes visible

    // 4 chunks of 32 keys: QK^T (swapped) -> exp2 -> in-reg transpose -> PV
#pragma unroll
    for (int kc2 = 0; kc2 < 4; ++kc2) {
      s8vec ak[2][2];
#pragma unroll
      for (int kbs = 0; kbs < 2; ++kbs) {
        const int row = (kc2 * 2 + kbs) * 16 + l15;
        ak[kbs][0] = *(const s8vec*)&Ks[row * 64 + ((0 + quad) ^ l7) * 8];
        ak[kbs][1] = *(const s8vec*)&Ks[row * 64 + ((4 + quad) ^ l7) * 8];
      }
      const int half = kc2 >> 1, G = (kc2 & 1) * 4 + quad;
      s8vec av[4];
#pragma unroll
      for (int nb = 0; nb < 4; ++nb)
        av[nb] = *(const s8vec*)&Vt[half][(nb * 16 + l15) * 64 + ((G) ^ l7) * 8];

      f4vec st[2][2];   // S^T: [key-sub][q-block]; lane: key=sub*16+quad*4+i, q=l15
#pragma unroll
      for (int kbs = 0; kbs < 2; ++kbs)
#pragma unroll
        for (int qb = 0; qb < 2; ++qb) {
          f4vec z;
#pragma unroll
          for (int i = 0; i < 4; ++i) z[i] = 0.f;
          z = mfma16(ak[kbs][0], bq[qb][0], z);
          st[kbs][qb] = mfma16(ak[kbs][1], bq[qb][1], z);
        }

#pragma unroll
      for (int qb = 0; qb < 2; ++qb) {
        float p0 = exp2f_fast(st[0][qb][0]), p1 = exp2f_fast(st[0][qb][1]);
        float p2 = exp2f_fast(st[0][qb][2]), p3 = exp2f_fast(st[0][qb][3]);
        float p4 = exp2f_fast(st[1][qb][0]), p5 = exp2f_fast(st[1][qb][1]);
        float p6 = exp2f_fast(st[1][qb][2]), p7 = exp2f_fast(st[1][qb][3]);
        lsum[qb] += ((p0 + p1) + (p2 + p3)) + ((p4 + p5) + (p6 + p7));
        // pack: wi = bf16 key-pairs {2q, 2q+1, 8+2q, 8+2q+1} (q = quad)
        unsigned w0 = pk2(p0, p1), w1 = pk2(p2, p3);
        unsigned w2 = pk2(p4, p5), w3 = pk2(p6, p7);
        // 2x2 reg-row transpose -> B-frag pairs {4q..4q+3}:
        // swap32: w0'=[w0.lo|w2.lo] w2'=[w0.hi|w2.hi]; swap16 interleaves rows.
        asm("v_permlane32_swap_b32 %0, %1" : "+v"(w0), "+v"(w2));
        asm("v_permlane16_swap_b32 %0, %1" : "+v"(w0), "+v"(w2));
        asm("v_permlane32_swap_b32 %0, %1" : "+v"(w1), "+v"(w3));
        asm("v_permlane16_swap_b32 %0, %1" : "+v"(w1), "+v"(w3));
        union { unsigned u[4]; s8vec v; } pb;
        pb.u[0] = w0; pb.u[1] = w1; pb.u[2] = w2; pb.u[3] = w3;
#pragma unroll
        for (int nb = 0; nb < 4; ++nb) o[nb][qb] = mfma16(av[nb], pb.v, o[nb][qb]);
      }
    }
  }

  // lsum: each lane has partial for q=qb*16+l15 over its keys; sum over quads.
  float inv[2];
#pragma unroll
  for (int qb = 0; qb < 2; ++qb) {
    float s = lsum[qb];
    s += __shfl_xor(s, 16, 64);
    s += __shfl_xor(s, 32, 64);
    inv[qb] = 1.0f / s;
  }

  // O^T[dv=nb*16+quad*4+i][q=qb*16+l15] -> out[b][s][h*64+dv]
  float* ob = out + ((size_t)b * S_ + qt * 128 + wid * 32) * D_ + h * DK_;
#pragma unroll
  for (int qb = 0; qb < 2; ++qb)
#pragma unroll
    for (int nb = 0; nb < 4; ++nb) {
      float4 vvv;
      vvv.x = o[nb][qb][0] * inv[qb];
      vvv.y = o[nb][qb][1] * inv[qb];
      vvv.z = o[nb][qb][2] * inv[qb];
      vvv.w = o[nb][qb][3] * inv[qb];
      *(float4*)&ob[(size_t)(qb * 16 + l15) * D_ + nb * 16 + quad * 4] = vvv;
    }
}

extern "C" void kernel_launch(void* const* d_in, const int* in_sizes, int n_in,
                              void* d_out, int out_size, void* d_ws, size_t ws_size,
                              hipStream_t stream) {
  const float* x  = (const float*)d_in[0];
  const float* Wq = (const float*)d_in[1];
  const float* Wk = (const float*)d_in[2];
  const float* Wv = (const float*)d_in[3];
  float* out = (float*)d_out;

  ushort* xb  = (ushort*)d_ws;                       // B*S*D bf16
  ushort* wbt = xb + (size_t)B_ * S_ * D_;           // [3072][1024] bf16
  ushort* qkv = wbt + (size_t)3 * D_ * D_;           // q,k: [b][h][s][64]; v: [b*1024+n1][s]
  const size_t per = (size_t)B_ * H_ * S_ * DK_;

  cvt_x<<<(B_ * S_ * D_) / 4 / 256, 256, 0, stream>>>(x, xb);
  cvt_w<<<dim3(16, 16, 3), 256, 0, stream>>>(Wq, Wk, Wv, wbt);
  proj_gemm<<<dim3(M_ / 128, N_ / 128), 256, 0, stream>>>(xb, wbt, qkv);
  attn<<<dim3(S_ / 128, B_ * H_), 256, 0, stream>>>(qkv, qkv + per, qkv + 2 * per, out);
}